// Round 1
// baseline (929.868 us; speedup 1.0000x reference)
//
#include <hip/hip_runtime.h>
#include <hip/hip_bf16.h>
#include <math.h>

// KoLeo loss: dist_i = sqrt(2 - 2*max_{j!=i} <fhat_i, fhat_j>); loss = -mean(log(dist+1e-8))
// Reduces to a row-max-of-Gram GEMM (16384^2 x 1024, 550 GFLOP) -> bf16 MFMA.

#define N_ROWS 16384
#define DIM 1024
#define BT 128   // Gram tile (rows and cols per block)
#define BK 64    // K tile staged per iteration

typedef __bf16 bf16x8 __attribute__((ext_vector_type(8)));
typedef float  f32x4  __attribute__((ext_vector_type(4)));

__device__ __forceinline__ unsigned short f2bf(float f) {
  // round-to-nearest-even fp32 -> bf16
  unsigned int b = __builtin_bit_cast(unsigned int, f);
  b += 0x7fffu + ((b >> 16) & 1u);
  return (unsigned short)(b >> 16);
}

__device__ __forceinline__ void async16(const void* g, void* l) {
  // global -> LDS direct copy, 16B per lane; LDS dest = wave-uniform base + lane*16
  __builtin_amdgcn_global_load_lds(
      (__attribute__((address_space(1))) const void*)g,
      (__attribute__((address_space(3))) void*)l, 16, 0, 0);
}

// ---------------------------------------------------------------- normalize
__global__ __launch_bounds__(256) void normalize_kernel(
    const float* __restrict__ in, unsigned short* __restrict__ outb) {
  const int row = blockIdx.x;
  const int t = threadIdx.x;  // 256 threads, 4 floats each
  const float4 v = ((const float4*)(in + (size_t)row * DIM))[t];
  float ss = v.x * v.x + v.y * v.y + v.z * v.z + v.w * v.w;
#pragma unroll
  for (int s = 1; s < 64; s <<= 1) ss += __shfl_xor(ss, s, 64);
  __shared__ float wsum[4];
  const int wave = t >> 6, lane = t & 63;
  if (lane == 0) wsum[wave] = ss;
  __syncthreads();
  const float tot = wsum[0] + wsum[1] + wsum[2] + wsum[3];
  const float scale = 1.f / fmaxf(sqrtf(tot), 1e-12f);
  ushort4 o;
  o.x = f2bf(v.x * scale);
  o.y = f2bf(v.y * scale);
  o.z = f2bf(v.z * scale);
  o.w = f2bf(v.w * scale);
  ((ushort4*)(outb + (size_t)row * DIM))[t] = o;
}

// -------------------------------------------------- Gram row-max (the GEMM)
// Block (jt, it) computes G-tile rows [it*128,+128) x cols [jt*128,+128),
// masks the diagonal, and writes per-row max to partial[jt][row].
__global__ __launch_bounds__(256) void gemm_rowmax(
    const unsigned short* __restrict__ F, float* __restrict__ partial) {
  __shared__ __align__(16) unsigned short sA[BT * BK];  // [row][k], stride BK
  __shared__ __align__(16) unsigned short sB[BT * BK];
  __shared__ float red[BT][2];

  const int jt = blockIdx.x, it = blockIdx.y;
  const int ibase = it * BT, jbase = jt * BT;
  const int tid = threadIdx.x;
  const int wave = tid >> 6, lane = tid & 63;
  const int wi = wave >> 1, wj = wave & 1;  // 2x2 wave grid, 64x64 each
  const int quad = lane >> 4, r16 = lane & 15;

  f32x4 acc[4][4] = {};  // [mi][ni], 16x16 tiles

  for (int k0 = 0; k0 < DIM; k0 += BK) {
    // stage A (rows ibase..+127) and B (rows jbase..+127), 16B/lane x 4 iters
#pragma unroll
    for (int q = 0; q < 4; ++q) {
      const int flatb = q * 256 + wave * 64;  // wave-uniform granule base
      const int flat = flatb + lane;          // 16B granule id = row*8 + k8
      const int row = flat >> 3;
      const int c8 = (flat & 7) << 3;
      async16(F + (size_t)(ibase + row) * DIM + k0 + c8,
              (char*)sA + (size_t)flatb * 16);
      async16(F + (size_t)(jbase + row) * DIM + k0 + c8,
              (char*)sB + (size_t)flatb * 16);
    }
    __syncthreads();
#pragma unroll
    for (int kk = 0; kk < BK; kk += 32) {
      bf16x8 afr[4], bfr[4];
#pragma unroll
      for (int mi = 0; mi < 4; ++mi)
        afr[mi] = *(const bf16x8*)(sA + (wi * 64 + mi * 16 + r16) * BK + kk + quad * 8);
#pragma unroll
      for (int ni = 0; ni < 4; ++ni)
        bfr[ni] = *(const bf16x8*)(sB + (wj * 64 + ni * 16 + r16) * BK + kk + quad * 8);
#pragma unroll
      for (int mi = 0; mi < 4; ++mi)
#pragma unroll
        for (int ni = 0; ni < 4; ++ni)
          acc[mi][ni] = __builtin_amdgcn_mfma_f32_16x16x32_bf16(
              afr[mi], bfr[ni], acc[mi][ni], 0, 0, 0);
    }
    __syncthreads();
  }

  // Row-max with diagonal mask. C/D layout: col=lane&15, row=quad*4+reg.
#pragma unroll
  for (int mi = 0; mi < 4; ++mi) {
#pragma unroll
    for (int r = 0; r < 4; ++r) {
      const int rowg = ibase + wi * 64 + mi * 16 + quad * 4 + r;
      float m = -INFINITY;
#pragma unroll
      for (int ni = 0; ni < 4; ++ni) {
        const int colg = jbase + wj * 64 + ni * 16 + r16;
        const float v = acc[mi][ni][r];
        m = (rowg == colg) ? m : fmaxf(m, v);
      }
      // reduce across the 16 col-lanes (xor 1,2,4,8 stays within the group)
#pragma unroll
      for (int s = 1; s < 16; s <<= 1) m = fmaxf(m, __shfl_xor(m, s, 64));
      if (r16 == 0) red[wi * 64 + mi * 16 + quad * 4 + r][wj] = m;
    }
  }
  __syncthreads();
  if (tid < BT)
    partial[(size_t)jt * N_ROWS + ibase + tid] = fmaxf(red[tid][0], red[tid][1]);
}

// ------------------------------------------------------------- reductions
__global__ __launch_bounds__(256) void row_reduce(
    const float* __restrict__ partial, float* __restrict__ blocksum) {
  const int r = blockIdx.x * 256 + threadIdx.x;
  float m = -INFINITY;
  for (int p = 0; p < N_ROWS / BT; ++p)
    m = fmaxf(m, partial[(size_t)p * N_ROWS + r]);
  const float d2 = fmaxf(2.f - 2.f * m, 0.f);
  float term = logf(sqrtf(d2) + 1e-8f);
#pragma unroll
  for (int s = 1; s < 64; s <<= 1) term += __shfl_xor(term, s, 64);
  __shared__ float wsum[4];
  const int wave = threadIdx.x >> 6, lane = threadIdx.x & 63;
  if (lane == 0) wsum[wave] = term;
  __syncthreads();
  if (threadIdx.x == 0)
    blocksum[blockIdx.x] = wsum[0] + wsum[1] + wsum[2] + wsum[3];
}

__global__ void finalize(const float* __restrict__ blocksum,
                         float* __restrict__ out) {
  float v = blocksum[threadIdx.x];  // 64 blocks -> 64 threads, one wave
#pragma unroll
  for (int s = 1; s < 64; s <<= 1) v += __shfl_xor(v, s, 64);
  if (threadIdx.x == 0) out[0] = -v / (float)N_ROWS;
}

// ---------------------------------------------------------------- launcher
extern "C" void kernel_launch(void* const* d_in, const int* in_sizes, int n_in,
                              void* d_out, int out_size, void* d_ws, size_t ws_size,
                              hipStream_t stream) {
  const float* feats = (const float*)d_in[0];
  float* out = (float*)d_out;
  char* ws = (char*)d_ws;

  // ws layout: [0, 32MB) bf16 normalized feats; [32MB, 40MB) partial max
  //            [128][16384] fp32; then 64 floats of block sums.
  unsigned short* fbf = (unsigned short*)ws;
  float* partial = (float*)(ws + (size_t)N_ROWS * DIM * 2);
  float* blocksum =
      (float*)(ws + (size_t)N_ROWS * DIM * 2 + (size_t)(N_ROWS / BT) * N_ROWS * 4);

  normalize_kernel<<<N_ROWS, 256, 0, stream>>>(feats, fbf);
  gemm_rowmax<<<dim3(N_ROWS / BT, N_ROWS / BT), 256, 0, stream>>>(fbf, partial);
  row_reduce<<<N_ROWS / 256, 256, 0, stream>>>(partial, blocksum);
  finalize<<<1, 64, 0, stream>>>(blocksum, out);
}

// Round 2
// 529.353 us; speedup vs baseline: 1.7566x; 1.7566x over previous
//
#include <hip/hip_runtime.h>
#include <hip/hip_bf16.h>
#include <math.h>

// KoLeo loss: dist_i = sqrt(2 - 2*max_{j!=i} <fhat_i, fhat_j>); loss = -mean(log(dist+1e-8))
// Row-max-of-Gram via bf16 MFMA. Symmetric: only upper-triangle tiles computed;
// each tile yields row-max (for block it) AND col-max (for block jt).
// LDS k-granule XOR swizzle kills the 16-way ds_read_b128 bank conflicts.

#define N_ROWS 16384
#define DIM 1024
#define BT 128   // Gram tile (rows and cols per block)
#define BK 64    // K tile staged per iteration

typedef __bf16 bf16x8 __attribute__((ext_vector_type(8)));
typedef float  f32x4  __attribute__((ext_vector_type(4)));

__device__ __forceinline__ unsigned short f2bf(float f) {
  unsigned int b = __builtin_bit_cast(unsigned int, f);
  b += 0x7fffu + ((b >> 16) & 1u);
  return (unsigned short)(b >> 16);
}

__device__ __forceinline__ void async16(const void* g, void* l) {
  // global -> LDS direct copy, 16B/lane; LDS dest = wave-uniform base + lane*16
  __builtin_amdgcn_global_load_lds(
      (__attribute__((address_space(1))) const void*)g,
      (__attribute__((address_space(3))) void*)l, 16, 0, 0);
}

// ---------------------------------------------------------------- normalize
__global__ __launch_bounds__(256) void normalize_kernel(
    const float* __restrict__ in, unsigned short* __restrict__ outb) {
  const int row = blockIdx.x;
  const int t = threadIdx.x;
  const float4 v = ((const float4*)(in + (size_t)row * DIM))[t];
  float ss = v.x * v.x + v.y * v.y + v.z * v.z + v.w * v.w;
#pragma unroll
  for (int s = 1; s < 64; s <<= 1) ss += __shfl_xor(ss, s, 64);
  __shared__ float wsum[4];
  const int wave = t >> 6, lane = t & 63;
  if (lane == 0) wsum[wave] = ss;
  __syncthreads();
  const float tot = wsum[0] + wsum[1] + wsum[2] + wsum[3];
  const float scale = 1.f / fmaxf(sqrtf(tot), 1e-12f);
  ushort4 o;
  o.x = f2bf(v.x * scale);
  o.y = f2bf(v.y * scale);
  o.z = f2bf(v.z * scale);
  o.w = f2bf(v.w * scale);
  ((ushort4*)(outb + (size_t)row * DIM))[t] = o;
}

// -------------------------------------------------- Gram row/col-max GEMM
// Tile (it=blockIdx.y, jt=blockIdx.x), active only for jt >= it.
// Writes row-max -> partial[jt][ibase+row], col-max -> partial[it][jbase+col]
// (diagonal tiles: row-max only, self-sim masked).
__global__ __launch_bounds__(256) void gemm_rowmax(
    const unsigned short* __restrict__ F, float* __restrict__ partial) {
  const int jt = blockIdx.x, it = blockIdx.y;
  if (jt < it) return;  // lower triangle handled by symmetry

  __shared__ __align__(16) unsigned short sA[BT * BK];  // [row][k-granule swizzled]
  __shared__ __align__(16) unsigned short sB[BT * BK];
  __shared__ float red[BT][2];   // row-max per wave-col
  __shared__ float redc[BT][2];  // col-max per wave-row

  const int ibase = it * BT, jbase = jt * BT;
  const int tid = threadIdx.x;
  const int wave = tid >> 6, lane = tid & 63;
  const int wi = wave >> 1, wj = wave & 1;  // 2x2 wave grid, 64x64 each
  const int quad = lane >> 4, r16 = lane & 15;

  f32x4 acc[4][4] = {};  // [mi][ni]

  for (int k0 = 0; k0 < DIM; k0 += BK) {
#pragma unroll
    for (int q = 0; q < 4; ++q) {
      const int flatb = q * 256 + wave * 64;  // wave-uniform granule base
      const int flat = flatb + lane;          // physical granule = row*8 + k8
      const int row = flat >> 3;
      const int k8 = flat & 7;
      const int c8 = (k8 ^ (row & 7)) << 3;   // XOR-swizzled global k offset
      async16(F + (size_t)(ibase + row) * DIM + k0 + c8,
              (char*)sA + (size_t)flatb * 16);
      async16(F + (size_t)(jbase + row) * DIM + k0 + c8,
              (char*)sB + (size_t)flatb * 16);
    }
    __syncthreads();
#pragma unroll
    for (int kk = 0; kk < BK; kk += 32) {
      const int g = (kk >> 3) + quad;  // logical k-granule for this lane
      bf16x8 afr[4], bfr[4];
#pragma unroll
      for (int mi = 0; mi < 4; ++mi) {
        const int R = wi * 64 + mi * 16 + r16;
        afr[mi] = *(const bf16x8*)(sA + (R * 8 + (g ^ (r16 & 7))) * 8);
      }
#pragma unroll
      for (int ni = 0; ni < 4; ++ni) {
        const int R = wj * 64 + ni * 16 + r16;
        bfr[ni] = *(const bf16x8*)(sB + (R * 8 + (g ^ (r16 & 7))) * 8);
      }
#pragma unroll
      for (int mi = 0; mi < 4; ++mi)
#pragma unroll
        for (int ni = 0; ni < 4; ++ni)
          acc[mi][ni] = __builtin_amdgcn_mfma_f32_16x16x32_bf16(
              afr[mi], bfr[ni], acc[mi][ni], 0, 0, 0);
    }
    __syncthreads();
  }

  // Row-max with diagonal mask. C/D layout: col=lane&15, row=quad*4+reg.
#pragma unroll
  for (int mi = 0; mi < 4; ++mi) {
#pragma unroll
    for (int r = 0; r < 4; ++r) {
      const int rowg = ibase + wi * 64 + mi * 16 + quad * 4 + r;
      float m = -INFINITY;
#pragma unroll
      for (int ni = 0; ni < 4; ++ni) {
        const int colg = jbase + wj * 64 + ni * 16 + r16;
        const float v = acc[mi][ni][r];
        m = (rowg == colg) ? m : fmaxf(m, v);
      }
#pragma unroll
      for (int s = 1; s < 16; s <<= 1) m = fmaxf(m, __shfl_xor(m, s, 64));
      if (r16 == 0) red[wi * 64 + mi * 16 + quad * 4 + r][wj] = m;
    }
  }

  // Col-max (off-diagonal tiles only; no diag elements present there).
  if (it != jt) {
#pragma unroll
    for (int ni = 0; ni < 4; ++ni) {
      float m = -INFINITY;
#pragma unroll
      for (int mi = 0; mi < 4; ++mi)
#pragma unroll
        for (int r = 0; r < 4; ++r) m = fmaxf(m, acc[mi][ni][r]);
      m = fmaxf(m, __shfl_xor(m, 16, 64));  // reduce across quad
      m = fmaxf(m, __shfl_xor(m, 32, 64));
      if (quad == 0) redc[wj * 64 + ni * 16 + r16][wi] = m;
    }
  }
  __syncthreads();
  if (tid < BT) {
    partial[(size_t)jt * N_ROWS + ibase + tid] = fmaxf(red[tid][0], red[tid][1]);
  } else if (it != jt) {
    const int c = tid - BT;
    partial[(size_t)it * N_ROWS + jbase + c] = fmaxf(redc[c][0], redc[c][1]);
  }
}

// ------------------------------------------------------------- reductions
__global__ __launch_bounds__(256) void row_reduce(
    const float* __restrict__ partial, float* __restrict__ blocksum) {
  const int r = blockIdx.x * 256 + threadIdx.x;
  float m = -INFINITY;
  for (int p = 0; p < N_ROWS / BT; ++p)
    m = fmaxf(m, partial[(size_t)p * N_ROWS + r]);
  const float d2 = fmaxf(2.f - 2.f * m, 0.f);
  float term = logf(sqrtf(d2) + 1e-8f);
#pragma unroll
  for (int s = 1; s < 64; s <<= 1) term += __shfl_xor(term, s, 64);
  __shared__ float wsum[4];
  const int wave = threadIdx.x >> 6, lane = threadIdx.x & 63;
  if (lane == 0) wsum[wave] = term;
  __syncthreads();
  if (threadIdx.x == 0)
    blocksum[blockIdx.x] = wsum[0] + wsum[1] + wsum[2] + wsum[3];
}

__global__ void finalize(const float* __restrict__ blocksum,
                         float* __restrict__ out) {
  float v = blocksum[threadIdx.x];
#pragma unroll
  for (int s = 1; s < 64; s <<= 1) v += __shfl_xor(v, s, 64);
  if (threadIdx.x == 0) out[0] = -v / (float)N_ROWS;
}

// ---------------------------------------------------------------- launcher
extern "C" void kernel_launch(void* const* d_in, const int* in_sizes, int n_in,
                              void* d_out, int out_size, void* d_ws, size_t ws_size,
                              hipStream_t stream) {
  const float* feats = (const float*)d_in[0];
  float* out = (float*)d_out;
  char* ws = (char*)d_ws;

  unsigned short* fbf = (unsigned short*)ws;
  float* partial = (float*)(ws + (size_t)N_ROWS * DIM * 2);
  float* blocksum =
      (float*)(ws + (size_t)N_ROWS * DIM * 2 + (size_t)(N_ROWS / BT) * N_ROWS * 4);

  normalize_kernel<<<N_ROWS, 256, 0, stream>>>(feats, fbf);
  gemm_rowmax<<<dim3(N_ROWS / BT, N_ROWS / BT), 256, 0, stream>>>(fbf, partial);
  row_reduce<<<N_ROWS / 256, 256, 0, stream>>>(partial, blocksum);
  finalize<<<1, 64, 0, stream>>>(blocksum, out);
}